// Round 14
// baseline (68.954 us; speedup 1.0000x reference)
//
#include <hip/hip_runtime.h>
#include <hip/hip_bf16.h>

// AttentionHead: B=4, T=4096, D=1024, DA=64, scale = 1/96 folded into q.
// R14: latency-depth round. proj: x-prefetch rotation 3 -> 5 slots (covers
// ~5 stage-times > HBM miss latency; barrier makes any wave's stall global).
// attn: V double-buffered (was same-step load->use; PV stalled on L2 each
// chunk). Both fully static indexing (rule: runtime-indexed arrays spill).

#define T_SEQ 4096
#define NW 12   // attention waves per block (3/SIMD; unified-reg cap 170)

using bf16x8 = __bf16 __attribute__((ext_vector_type(8)));
using f32x16 = float __attribute__((ext_vector_type(16)));
using uint4v = unsigned int __attribute__((ext_vector_type(4)));

static constexpr float QSCALE = 1.4426950408889634f / 96.0f;

__device__ __forceinline__ unsigned short bf1(float v) {
    unsigned u = __builtin_bit_cast(unsigned, v);
    u += 0x7FFFu + ((u >> 16) & 1u);
    return (unsigned short)(u >> 16);
}
__device__ __forceinline__ unsigned cvt2(float lo, float hi) {
    unsigned r;
    asm("v_cvt_pk_bf16_f32 %0, %1, %2" : "=v"(r) : "v"(lo), "v"(hi));
    return r;
}
// v_permlane32_swap: ONLY safe when a,b hold DISTINCT values (see R8 note).
__device__ __forceinline__ void pswap(unsigned& a, unsigned& b) {
    asm volatile("v_permlane32_swap_b32 %0, %1" : "+v"(a), "+v"(b));
}
__device__ __forceinline__ float bflo(unsigned u) {
    return __builtin_bit_cast(float, u << 16);
}
__device__ __forceinline__ float bfhi(unsigned u) {
    return __builtin_bit_cast(float, u & 0xFFFF0000u);
}
__device__ __forceinline__ f32x16 zero16() {
    f32x16 z;
#pragma unroll
    for (int i = 0; i < 16; ++i) z[i] = 0.0f;
    return z;
}
#define MFMA32(a, b, c) __builtin_amdgcn_mfma_f32_32x32x16_bf16(a, b, c, 0, 0, 0)

// ---------------- kernel 1: W -> Wt3 frag-linear bf16 ----------------
// Wt3 flat: ((kt*6 + ct)*4 + kk)*512 + lane*8 + e
//   where col cg = ct*32 + (lane&31), k = kt*64 + kk*16 + (lane>>5)*8 + e.
__global__ __launch_bounds__(256) void prep_w(
        const float* __restrict__ Wq, const float* __restrict__ Wk,
        const float* __restrict__ Wv, const float* __restrict__ bq,
        const float* __restrict__ bk, const float* __restrict__ bv,
        unsigned short* __restrict__ Wt3, float* __restrict__ bias_t) {
    __shared__ float tile[64][65];
    const int tid = threadIdx.x;
    const int m = blockIdx.x >> 4, kt = blockIdx.x & 15, d0 = kt * 64;
    const float* W = (m == 0) ? Wq : (m == 1) ? Wk : Wv;
    const int a = tid & 63, r4 = tid >> 6;
#pragma unroll
    for (int j = 0; j < 16; ++j) {
        const int rr = r4 + 4 * j;
        tile[rr][a] = W[(size_t)(d0 + rr) * 64 + a];
    }
    __syncthreads();
    const float scl = (m == 0) ? QSCALE : 1.0f;
    const int dc = tid & 63, ar = tid >> 6;
#pragma unroll
    for (int j = 0; j < 16; ++j) {
        const int aa = ar + 4 * j;
        const int cg = m * 64 + aa;
        const size_t addr =
            ((size_t)(kt * 6 + (cg >> 5)) * 4 + (dc >> 4)) * 512 +
            ((cg & 31) + 32 * ((dc >> 3) & 1)) * 8 + (dc & 7);
        Wt3[addr] = bf1(tile[dc][aa] * scl);
    }
    if (kt == 0 && tid < 64) {
        const float* bb = (m == 0) ? bq : (m == 1) ? bk : bv;
        bias_t[m * 64 + tid] = bb[tid] * scl;
    }
}

// ---------------- kernel 2: QKV projection (v5: 5-deep prefetch) ----------
// 256 blocks x 768 thr = 12 waves (rh, ct). 64 rows, full K=1024, 16 stages,
// 5-slot static x-prefetch rotation, pad-68 A-tile, frag-linear B.
__global__ __launch_bounds__(768, 3) void proj_kernel(
        const float* __restrict__ x, const unsigned short* __restrict__ Wt3,
        const float* __restrict__ bias_t, unsigned short* __restrict__ qs,
        unsigned short* __restrict__ ksf, unsigned short* __restrict__ vtf) {
    __shared__ unsigned short Ald[2][64 * 68];   // 2 x 8.5 KB bf16

    const int tid = threadIdx.x;
    const int w = tid >> 6, l = tid & 63, g = l >> 5, c32 = l & 31;
    const int rh = w & 1, ct = w >> 1;
    const int rowbase = blockIdx.x * 64;

    const int r0 = tid >> 4, k40 = tid & 15;
    const int r1 = (tid + 768) >> 4, k41 = tid & 15;
    const bool haveB = (tid < 256);
    const float* xb0 = x + (size_t)(rowbase + r0) * 1024 + k40 * 4;
    const float* xb1 = x + (size_t)(rowbase + r1) * 1024 + k41 * 4;
    const int wo0 = r0 * 68 + k40 * 4;
    const int wo1 = r1 * 68 + k41 * 4;

    const unsigned short* Wb = Wt3 + (size_t)(ct * 4) * 512 + l * 8;
    const int aro = (rh * 32 + c32) * 68;

    f32x16 acc = zero16();
    float4 ra[5], rb[5];   // 5-slot static rotation (stage s -> slot s%5)

    {
        float4 a0 = *(const float4*)(xb0);
        float4 b0;
        if (haveB) b0 = *(const float4*)(xb1);
        *(uint2*)(Ald[0] + wo0) = make_uint2(cvt2(a0.x, a0.y), cvt2(a0.z, a0.w));
        if (haveB)
            *(uint2*)(Ald[0] + wo1) = make_uint2(cvt2(b0.x, b0.y), cvt2(b0.z, b0.w));
    }
#pragma unroll
    for (int s = 1; s <= 5; ++s) {
        ra[s % 5] = *(const float4*)(xb0 + s * 64);
        if (haveB) rb[s % 5] = *(const float4*)(xb1 + s * 64);
    }
    asm volatile("s_waitcnt lgkmcnt(0)" ::: "memory");
    __builtin_amdgcn_s_barrier();
    __builtin_amdgcn_sched_barrier(0);

#pragma unroll
    for (int kt = 0; kt < 16; ++kt) {
        const unsigned short* A = Ald[kt & 1];
        const unsigned short* Wkt = Wb + (size_t)kt * 12288;
        bf16x8 b0 = *(const bf16x8*)(Wkt);
        bf16x8 b1 = *(const bf16x8*)(Wkt + 512);
        bf16x8 b2 = *(const bf16x8*)(Wkt + 1024);
        bf16x8 b3 = *(const bf16x8*)(Wkt + 1536);
        // write stage kt+1 (its load was issued 5 stages ago)
        if (kt < 15) {
            float4 a = ra[(kt + 1) % 5];
            *(uint2*)(Ald[(kt + 1) & 1] + wo0) =
                make_uint2(cvt2(a.x, a.y), cvt2(a.z, a.w));
            if (haveB) {
                float4 b4 = rb[(kt + 1) % 5];
                *(uint2*)(Ald[(kt + 1) & 1] + wo1) =
                    make_uint2(cvt2(b4.x, b4.y), cvt2(b4.z, b4.w));
            }
        }
        // refill freed slot with stage kt+6
        if (kt < 10) {
            ra[(kt + 6) % 5] = *(const float4*)(xb0 + (kt + 6) * 64);
            if (haveB) rb[(kt + 6) % 5] = *(const float4*)(xb1 + (kt + 6) * 64);
        }
        {
            bf16x8 a0 = *(const bf16x8*)(A + aro + (0 + g) * 8);
            bf16x8 a1 = *(const bf16x8*)(A + aro + (2 + g) * 8);
            bf16x8 a2 = *(const bf16x8*)(A + aro + (4 + g) * 8);
            bf16x8 a3 = *(const bf16x8*)(A + aro + (6 + g) * 8);
            acc = MFMA32(a0, b0, acc);
            acc = MFMA32(a1, b1, acc);
            acc = MFMA32(a2, b2, acc);
            acc = MFMA32(a3, b3, acc);
        }
        asm volatile("s_waitcnt lgkmcnt(0)" ::: "memory");
        __builtin_amdgcn_s_barrier();
        __builtin_amdgcn_sched_barrier(0);
    }

    // epilogue
    const int cg = ct * 32 + c32;
    const float bias = bias_t[cg];
    const int mat = cg >> 6, cm = cg & 63;
    if (mat == 2) {
#pragma unroll
        for (int q4 = 0; q4 < 4; ++q4) {
            const int rowg = rowbase + rh * 32 + 8 * q4 + 4 * g;
            const int b = rowg >> 12, tl = rowg & (T_SEQ - 1);
            const int ch = tl >> 5;
            const int f = (cm >> 5) * 2 + (q4 >> 1);
            const int lane = (cm & 31) + 32 * (q4 & 1);
            unsigned lo = cvt2(acc[4 * q4 + 0] + bias, acc[4 * q4 + 1] + bias);
            unsigned hi = cvt2(acc[4 * q4 + 2] + bias, acc[4 * q4 + 3] + bias);
            *(uint2*)(vtf + ((size_t)b * 128 + ch) * 2048 + f * 512 +
                      lane * 8 + 4 * g) = make_uint2(lo, hi);
        }
    } else if (mat == 1) {
#pragma unroll
        for (int r = 0; r < 16; ++r) {
            const int rowg = rowbase + rh * 32 + (r & 3) + 8 * (r >> 2) + 4 * g;
            const int b = rowg >> 12, tl = rowg & (T_SEQ - 1);
            ksf[((size_t)b * 128 + (tl >> 5)) * 2048 + (cm >> 4) * 512 +
                ((tl & 31) + 32 * ((cm >> 3) & 1)) * 8 + (cm & 7)] =
                bf1(acc[r] + bias);
        }
    } else {
#pragma unroll
        for (int r = 0; r < 16; ++r) {
            const int rowg = rowbase + rh * 32 + (r & 3) + 8 * (r >> 2) + 4 * g;
            qs[(size_t)rowg * 64 + cm] = bf1(acc[r] + bias);
        }
    }
}

// ---------------- kernel 3: causal flash attention ----------------
// R13 structure + V double-buffer: K AND V now both prefetched 1 chunk
// ahead (V was same-step load->use; PV stalled on L2 every chunk).
__global__ __launch_bounds__(768, 3) void attn_kernel(
        const unsigned short* __restrict__ qs, const unsigned short* __restrict__ ksf,
        const unsigned short* __restrict__ vtf, float* __restrict__ out) {
    __shared__ unsigned short Osh[NW][32][66];
    __shared__ float msh[NW][32];
    __shared__ float ssh[NW][32];

    const int tid = threadIdx.x;
    const int w = tid >> 6, l = tid & 63, g = l >> 5, c32 = l & 31;
    const int b = blockIdx.x & 3;
    const int pid = blockIdx.x >> 2;

    for (int tt = 0; tt < 2; ++tt) {
        const int jt = tt ? pid : 127 - pid;
        const int qbase = jt * 32;

        const unsigned short* qp =
            qs + ((size_t)b * T_SEQ + qbase + c32) * 64 + g * 8;
        bf16x8 qf[4];
#pragma unroll
        for (int t = 0; t < 4; ++t) qf[t] = *(const bf16x8*)(qp + 16 * t);

        const unsigned short* pKc = ksf + ((size_t)b * 128 + w) * 2048 + l * 8;
        const unsigned short* pVc = vtf + ((size_t)b * 128 + w) * 2048 + l * 8;

        auto loadK = [&](bf16x8(&kf)[4]) {
#pragma unroll
            for (int t = 0; t < 4; ++t)
                kf[t] = *(const bf16x8*)(pKc + t * 512);
            pKc += NW * 2048;
        };
        auto loadV = [&](bf16x8(&vf)[4]) {
#pragma unroll
            for (int f = 0; f < 4; ++f)
                vf[f] = *(const bf16x8*)(pVc + f * 512);
            pVc += NW * 2048;
        };

        const int nch = (jt >= w) ? (jt - w) / NW + 1 : 0;
        const bool hasDiag = (jt >= w) && ((jt - w) % NW == 0);
        float m = -INFINITY, ssum = 0.0f;
        f32x16 o0 = zero16(), o1 = zero16();
        f32x16 s_cur;
        bf16x8 k0[4], k1[4], v0[4], v1[4];

        if (nch > 0) {
            loadK(k0);
            loadV(v0);
            f32x16 t = zero16();
#pragma unroll
            for (int t4 = 0; t4 < 4; ++t4) t = MFMA32(k0[t4], qf[t4], t);
            s_cur = t;
        }

        // STEP i: softmax(s_cur of chunk i), PV with vc, prefetch K/V for
        // i+1 into kn/vn, QK(i+1) with kn at the end.
        auto STEP = [&](bf16x8(&kn)[4], bf16x8(&vc)[4], bf16x8(&vn)[4], int i) {
            if (i + 1 < nch) { loadV(vn); loadK(kn); }   // chunk i+1 in flight
            if (hasDiag && i == nch - 1) {
#pragma unroll
                for (int r = 0; r < 16; ++r) {
                    const int kl = (r & 3) + 8 * (r >> 2) + 4 * g;
                    if (kl > c32) s_cur[r] = -1e30f;
                }
            }
            float a0 = fmaxf(fmaxf(s_cur[0], s_cur[1]), fmaxf(s_cur[2], s_cur[3]));
            float a1 = fmaxf(fmaxf(s_cur[4], s_cur[5]), fmaxf(s_cur[6], s_cur[7]));
            float a2 = fmaxf(fmaxf(s_cur[8], s_cur[9]), fmaxf(s_cur[10], s_cur[11]));
            float a3 = fmaxf(fmaxf(s_cur[12], s_cur[13]), fmaxf(s_cur[14], s_cur[15]));
            float pm = fmaxf(fmaxf(a0, a1), fmaxf(a2, a3));
            if (!__all(pm <= m + 8.0f)) {
                float rmax = fmaxf(pm, __shfl_xor(pm, 32, 64));
                const float mn = fmaxf(m, rmax);
                const float alpha = exp2f(m - mn);
#pragma unroll
                for (int r = 0; r < 16; ++r) { o0[r] *= alpha; o1[r] *= alpha; }
                ssum *= alpha;
                m = mn;
            }
            float p[16];
#pragma unroll
            for (int r = 0; r < 16; ++r) p[r] = exp2f(s_cur[r] - m);
            float s0 = (p[0] + p[1]) + (p[2] + p[3]);
            float s1 = (p[4] + p[5]) + (p[6] + p[7]);
            float s2 = (p[8] + p[9]) + (p[10] + p[11]);
            float s3 = (p[12] + p[13]) + (p[14] + p[15]);
            ssum += (s0 + s1) + (s2 + s3);
            unsigned c01 = cvt2(p[0], p[1]), c23 = cvt2(p[2], p[3]);
            unsigned c45 = cvt2(p[4], p[5]), c67 = cvt2(p[6], p[7]);
            pswap(c01, c45); pswap(c23, c67);
            unsigned c89 = cvt2(p[8], p[9]), cab = cvt2(p[10], p[11]);
            unsigned ccd = cvt2(p[12], p[13]), cef = cvt2(p[14], p[15]);
            pswap(c89, ccd); pswap(cab, cef);
            uint4v u0; u0[0] = c01; u0[1] = c23; u0[2] = c45; u0[3] = c67;
            uint4v u1; u1[0] = c89; u1[1] = cab; u1[2] = ccd; u1[3] = cef;
            bf16x8 pb0 = __builtin_bit_cast(bf16x8, u0);
            bf16x8 pb1 = __builtin_bit_cast(bf16x8, u1);
            __builtin_amdgcn_s_setprio(1);
            o0 = MFMA32(vc[0], pb0, o0);
            o0 = MFMA32(vc[1], pb1, o0);
            o1 = MFMA32(vc[2], pb0, o1);
            o1 = MFMA32(vc[3], pb1, o1);
            if (i + 1 < nch) {
                f32x16 t = zero16();
#pragma unroll
                for (int t4 = 0; t4 < 4; ++t4) t = MFMA32(kn[t4], qf[t4], t);
                s_cur = t;
            }
            __builtin_amdgcn_s_setprio(0);
        };

        int i = 0;
        while (i < nch) {
            STEP(k1, v0, v1, i); ++i;
            if (i < nch) { STEP(k0, v1, v0, i); ++i; }
        }
        ssum += __shfl_xor(ssum, 32, 64);

        if (l < 32) { msh[w][l] = m; ssh[w][l] = ssum; }
#pragma unroll
        for (int q4 = 0; q4 < 4; ++q4) {
            const int base = 8 * q4 + 4 * g;
            *(unsigned*)&Osh[w][c32][base]      = cvt2(o0[4 * q4], o0[4 * q4 + 1]);
            *(unsigned*)&Osh[w][c32][base + 2]  = cvt2(o0[4 * q4 + 2], o0[4 * q4 + 3]);
            *(unsigned*)&Osh[w][c32][base + 32] = cvt2(o1[4 * q4], o1[4 * q4 + 1]);
            *(unsigned*)&Osh[w][c32][base + 34] = cvt2(o1[4 * q4 + 2], o1[4 * q4 + 3]);
        }
        __syncthreads();

        if (tid < 512) {
            const int qrow = tid >> 4, e4 = tid & 15;
            float M = -INFINITY;
            float mw[NW];
#pragma unroll
            for (int u = 0; u < NW; ++u) { mw[u] = msh[u][qrow]; M = fmaxf(M, mw[u]); }
            float den = 0.0f;
            float r0 = 0.f, r1 = 0.f, r2 = 0.f, r3 = 0.f;
#pragma unroll
            for (int u = 0; u < NW; ++u) {
                const float scu = exp2f(mw[u] - M);
                den += ssh[u][qrow] * scu;
                const unsigned ua = *(const unsigned*)&Osh[u][qrow][4 * e4];
                const unsigned ub = *(const unsigned*)&Osh[u][qrow][4 * e4 + 2];
                r0 += bflo(ua) * scu;
                r1 += bfhi(ua) * scu;
                r2 += bflo(ub) * scu;
                r3 += bfhi(ub) * scu;
            }
            const float inv = 1.0f / den;
            float4 st;
            st.x = r0 * inv; st.y = r1 * inv; st.z = r2 * inv; st.w = r3 * inv;
            *(float4*)(out + ((size_t)b * T_SEQ + qbase + qrow) * 64 + 4 * e4) = st;
        }
        __syncthreads();
    }
}

// ---------------- launch ----------------
extern "C" void kernel_launch(void* const* d_in, const int* in_sizes, int n_in,
                              void* d_out, int out_size, void* d_ws, size_t ws_size,
                              hipStream_t stream) {
    const float* x  = (const float*)d_in[0];
    const float* Wq = (const float*)d_in[1];
    const float* bq = (const float*)d_in[2];
    const float* Wk = (const float*)d_in[3];
    const float* bk = (const float*)d_in[4];
    const float* Wv = (const float*)d_in[5];
    const float* bv = (const float*)d_in[6];
    float* out = (float*)d_out;

    char* ws = (char*)d_ws;
    unsigned short* Wt3    = (unsigned short*)(ws);                 // 384 KB
    float*          bias_t = (float*)(ws + 393216);                 // 768 B
    unsigned short* qsb    = (unsigned short*)(ws + (1u << 20));    // 2 MB
    unsigned short* ksb    = (unsigned short*)(ws + (3u << 20));    // 2 MB
    unsigned short* vtb    = (unsigned short*)(ws + (5u << 20));    // 2 MB

    prep_w<<<48, 256, 0, stream>>>(Wq, Wk, Wv, bq, bk, bv, Wt3, bias_t);
    proj_kernel<<<256, 768, 0, stream>>>(x, Wt3, bias_t, qsb, ksb, vtb);
    attn_kernel<<<256, 768, 0, stream>>>(qsb, ksb, vtb, out);
}

// Round 15
// 61.392 us; speedup vs baseline: 1.1232x; 1.1232x over previous
//
#include <hip/hip_runtime.h>
#include <hip/hip_bf16.h>

// AttentionHead: B=4, T=4096, D=1024, DA=64, scale = 1/96 folded into q.
// R15 = R13 exact revert + ONE change: proj B-operand double-buffer
// (stage kt issues kt+1's B loads at its top; L2 latency hides under
// LDS-write + ds_read + MFMA instead of stalling every barrier-locked
// stage). attn = R13 verbatim (R14's bundle regressed; attribution reset).

#define T_SEQ 4096
#define NW 12   // attention waves per block (3/SIMD; unified-reg cap 170)

using bf16x8 = __bf16 __attribute__((ext_vector_type(8)));
using f32x16 = float __attribute__((ext_vector_type(16)));
using uint4v = unsigned int __attribute__((ext_vector_type(4)));

static constexpr float QSCALE = 1.4426950408889634f / 96.0f;

__device__ __forceinline__ unsigned short bf1(float v) {
    unsigned u = __builtin_bit_cast(unsigned, v);
    u += 0x7FFFu + ((u >> 16) & 1u);
    return (unsigned short)(u >> 16);
}
__device__ __forceinline__ unsigned cvt2(float lo, float hi) {
    unsigned r;
    asm("v_cvt_pk_bf16_f32 %0, %1, %2" : "=v"(r) : "v"(lo), "v"(hi));
    return r;
}
// v_permlane32_swap: ONLY safe when a,b hold DISTINCT values (see R8 note).
__device__ __forceinline__ void pswap(unsigned& a, unsigned& b) {
    asm volatile("v_permlane32_swap_b32 %0, %1" : "+v"(a), "+v"(b));
}
__device__ __forceinline__ float bflo(unsigned u) {
    return __builtin_bit_cast(float, u << 16);
}
__device__ __forceinline__ float bfhi(unsigned u) {
    return __builtin_bit_cast(float, u & 0xFFFF0000u);
}
__device__ __forceinline__ f32x16 zero16() {
    f32x16 z;
#pragma unroll
    for (int i = 0; i < 16; ++i) z[i] = 0.0f;
    return z;
}
#define MFMA32(a, b, c) __builtin_amdgcn_mfma_f32_32x32x16_bf16(a, b, c, 0, 0, 0)

// ---------------- kernel 1: W -> Wt3 frag-linear bf16 ----------------
// Wt3 flat: ((kt*6 + ct)*4 + kk)*512 + lane*8 + e
//   where col cg = ct*32 + (lane&31), k = kt*64 + kk*16 + (lane>>5)*8 + e.
__global__ __launch_bounds__(256) void prep_w(
        const float* __restrict__ Wq, const float* __restrict__ Wk,
        const float* __restrict__ Wv, const float* __restrict__ bq,
        const float* __restrict__ bk, const float* __restrict__ bv,
        unsigned short* __restrict__ Wt3, float* __restrict__ bias_t) {
    __shared__ float tile[64][65];
    const int tid = threadIdx.x;
    const int m = blockIdx.x >> 4, kt = blockIdx.x & 15, d0 = kt * 64;
    const float* W = (m == 0) ? Wq : (m == 1) ? Wk : Wv;
    const int a = tid & 63, r4 = tid >> 6;
#pragma unroll
    for (int j = 0; j < 16; ++j) {
        const int rr = r4 + 4 * j;
        tile[rr][a] = W[(size_t)(d0 + rr) * 64 + a];
    }
    __syncthreads();
    const float scl = (m == 0) ? QSCALE : 1.0f;
    const int dc = tid & 63, ar = tid >> 6;
#pragma unroll
    for (int j = 0; j < 16; ++j) {
        const int aa = ar + 4 * j;
        const int cg = m * 64 + aa;
        const size_t addr =
            ((size_t)(kt * 6 + (cg >> 5)) * 4 + (dc >> 4)) * 512 +
            ((cg & 31) + 32 * ((dc >> 3) & 1)) * 8 + (dc & 7);
        Wt3[addr] = bf1(tile[dc][aa] * scl);
    }
    if (kt == 0 && tid < 64) {
        const float* bb = (m == 0) ? bq : (m == 1) ? bk : bv;
        bias_t[m * 64 + tid] = bb[tid] * scl;
    }
}

// ---------------- kernel 2: QKV projection (R13 + B double-buffer) --------
// 256 blocks x 768 thr = 12 waves (rh, ct). 64 rows, full K=1024, 16 stages,
// 3-deep x prefetch, pad-68 A-tile, frag-linear B prefetched 1 stage ahead.
__global__ __launch_bounds__(768, 3) void proj_kernel(
        const float* __restrict__ x, const unsigned short* __restrict__ Wt3,
        const float* __restrict__ bias_t, unsigned short* __restrict__ qs,
        unsigned short* __restrict__ ksf, unsigned short* __restrict__ vtf) {
    __shared__ unsigned short Ald[2][64 * 68];   // 2 x 8.5 KB bf16

    const int tid = threadIdx.x;
    const int w = tid >> 6, l = tid & 63, g = l >> 5, c32 = l & 31;
    const int rh = w & 1, ct = w >> 1;
    const int rowbase = blockIdx.x * 64;

    const int r0 = tid >> 4, k40 = tid & 15;
    const int r1 = (tid + 768) >> 4, k41 = tid & 15;
    const bool haveB = (tid < 256);
    const float* xb0 = x + (size_t)(rowbase + r0) * 1024 + k40 * 4;
    const float* xb1 = x + (size_t)(rowbase + r1) * 1024 + k41 * 4;
    const int wo0 = r0 * 68 + k40 * 4;
    const int wo1 = r1 * 68 + k41 * 4;

    const unsigned short* Wb = Wt3 + (size_t)(ct * 4) * 512 + l * 8;
    const int aro = (rh * 32 + c32) * 68;

    f32x16 acc = zero16();
    float4 ra[3], rb[3];   // 3-slot static rotation (R13 proven)
    bf16x8 bA[4], bB[4];   // B double-buffer (NEW)

    {
        float4 a0 = *(const float4*)(xb0);
        float4 b0;
        if (haveB) b0 = *(const float4*)(xb1);
        *(uint2*)(Ald[0] + wo0) = make_uint2(cvt2(a0.x, a0.y), cvt2(a0.z, a0.w));
        if (haveB)
            *(uint2*)(Ald[0] + wo1) = make_uint2(cvt2(b0.x, b0.y), cvt2(b0.z, b0.w));
    }
#pragma unroll
    for (int s = 1; s <= 3; ++s) {
        ra[s % 3] = *(const float4*)(xb0 + s * 64);
        if (haveB) rb[s % 3] = *(const float4*)(xb1 + s * 64);
    }
    // B for stage 0 (latency covered by the prologue barrier)
#pragma unroll
    for (int f = 0; f < 4; ++f) bA[f] = *(const bf16x8*)(Wb + f * 512);
    asm volatile("s_waitcnt lgkmcnt(0)" ::: "memory");
    __builtin_amdgcn_s_barrier();
    __builtin_amdgcn_sched_barrier(0);

    auto STAGE = [&](bf16x8(&bc)[4], bf16x8(&bn)[4], int kt) {
        const unsigned short* A = Ald[kt & 1];
        // (1) issue NEXT stage's B loads first — hide L2 latency under
        //     this stage's LDS-write + ds_read + MFMA
        if (kt < 15) {
            const unsigned short* Wn = Wb + (size_t)(kt + 1) * 12288;
#pragma unroll
            for (int f = 0; f < 4; ++f) bn[f] = *(const bf16x8*)(Wn + f * 512);
        }
        // (2) write stage kt+1 x data (loaded 3 stages ago)
        if (kt < 15) {
            float4 a = ra[(kt + 1) % 3];
            *(uint2*)(Ald[(kt + 1) & 1] + wo0) =
                make_uint2(cvt2(a.x, a.y), cvt2(a.z, a.w));
            if (haveB) {
                float4 b4 = rb[(kt + 1) % 3];
                *(uint2*)(Ald[(kt + 1) & 1] + wo1) =
                    make_uint2(cvt2(b4.x, b4.y), cvt2(b4.z, b4.w));
            }
        }
        // (3) refill freed x slot with stage kt+4
        if (kt < 12) {
            ra[(kt + 4) % 3] = *(const float4*)(xb0 + (kt + 4) * 64);
            if (haveB) rb[(kt + 4) % 3] = *(const float4*)(xb1 + (kt + 4) * 64);
        }
        // (4) ds_read A + MFMA with the ALREADY-LOADED bc
        {
            bf16x8 a0 = *(const bf16x8*)(A + aro + (0 + g) * 8);
            bf16x8 a1 = *(const bf16x8*)(A + aro + (2 + g) * 8);
            bf16x8 a2 = *(const bf16x8*)(A + aro + (4 + g) * 8);
            bf16x8 a3 = *(const bf16x8*)(A + aro + (6 + g) * 8);
            acc = MFMA32(a0, bc[0], acc);
            acc = MFMA32(a1, bc[1], acc);
            acc = MFMA32(a2, bc[2], acc);
            acc = MFMA32(a3, bc[3], acc);
        }
        asm volatile("s_waitcnt lgkmcnt(0)" ::: "memory");
        __builtin_amdgcn_s_barrier();
        __builtin_amdgcn_sched_barrier(0);
    };

#pragma unroll
    for (int kt = 0; kt < 16; kt += 2) {
        STAGE(bA, bB, kt);
        STAGE(bB, bA, kt + 1);
    }

    // epilogue
    const int cg = ct * 32 + c32;
    const float bias = bias_t[cg];
    const int mat = cg >> 6, cm = cg & 63;
    if (mat == 2) {
#pragma unroll
        for (int q4 = 0; q4 < 4; ++q4) {
            const int rowg = rowbase + rh * 32 + 8 * q4 + 4 * g;
            const int b = rowg >> 12, tl = rowg & (T_SEQ - 1);
            const int ch = tl >> 5;
            const int f = (cm >> 5) * 2 + (q4 >> 1);
            const int lane = (cm & 31) + 32 * (q4 & 1);
            unsigned lo = cvt2(acc[4 * q4 + 0] + bias, acc[4 * q4 + 1] + bias);
            unsigned hi = cvt2(acc[4 * q4 + 2] + bias, acc[4 * q4 + 3] + bias);
            *(uint2*)(vtf + ((size_t)b * 128 + ch) * 2048 + f * 512 +
                      lane * 8 + 4 * g) = make_uint2(lo, hi);
        }
    } else if (mat == 1) {
#pragma unroll
        for (int r = 0; r < 16; ++r) {
            const int rowg = rowbase + rh * 32 + (r & 3) + 8 * (r >> 2) + 4 * g;
            const int b = rowg >> 12, tl = rowg & (T_SEQ - 1);
            ksf[((size_t)b * 128 + (tl >> 5)) * 2048 + (cm >> 4) * 512 +
                ((tl & 31) + 32 * ((cm >> 3) & 1)) * 8 + (cm & 7)] =
                bf1(acc[r] + bias);
        }
    } else {
#pragma unroll
        for (int r = 0; r < 16; ++r) {
            const int rowg = rowbase + rh * 32 + (r & 3) + 8 * (r >> 2) + 4 * g;
            qs[(size_t)rowg * 64 + cm] = bf1(acc[r] + bias);
        }
    }
}

// ---------------- kernel 3: causal flash attention (R13 verbatim) --------
__global__ __launch_bounds__(768, 3) void attn_kernel(
        const unsigned short* __restrict__ qs, const unsigned short* __restrict__ ksf,
        const unsigned short* __restrict__ vtf, float* __restrict__ out) {
    __shared__ unsigned short Osh[NW][32][66];
    __shared__ float msh[NW][32];
    __shared__ float ssh[NW][32];

    const int tid = threadIdx.x;
    const int w = tid >> 6, l = tid & 63, g = l >> 5, c32 = l & 31;
    const int b = blockIdx.x & 3;
    const int pid = blockIdx.x >> 2;

    for (int tt = 0; tt < 2; ++tt) {
        const int jt = tt ? pid : 127 - pid;
        const int qbase = jt * 32;

        const unsigned short* qp =
            qs + ((size_t)b * T_SEQ + qbase + c32) * 64 + g * 8;
        bf16x8 qf[4];
#pragma unroll
        for (int t = 0; t < 4; ++t) qf[t] = *(const bf16x8*)(qp + 16 * t);

        const unsigned short* pKc = ksf + ((size_t)b * 128 + w) * 2048 + l * 8;
        const unsigned short* pVc = vtf + ((size_t)b * 128 + w) * 2048 + l * 8;

        auto loadK = [&](bf16x8(&kf)[4]) {
#pragma unroll
            for (int t = 0; t < 4; ++t)
                kf[t] = *(const bf16x8*)(pKc + t * 512);
            pKc += NW * 2048;
        };
        auto loadV = [&](bf16x8(&vf)[4]) {
#pragma unroll
            for (int f = 0; f < 4; ++f)
                vf[f] = *(const bf16x8*)(pVc + f * 512);
            pVc += NW * 2048;
        };

        const int nch = (jt >= w) ? (jt - w) / NW + 1 : 0;
        const bool hasDiag = (jt >= w) && ((jt - w) % NW == 0);
        float m = -INFINITY, ssum = 0.0f;
        f32x16 o0 = zero16(), o1 = zero16();
        f32x16 s_cur;
        bf16x8 k0[4], k1[4], vR[4];

        if (nch > 0) {
            loadK(k0);
            f32x16 t = zero16();
#pragma unroll
            for (int t4 = 0; t4 < 4; ++t4) t = MFMA32(k0[t4], qf[t4], t);
            s_cur = t;
        }

        auto STEP = [&](bf16x8(&kn)[4], int i) {
            loadV(vR);
            if (i + 1 < nch) loadK(kn);
            if (hasDiag && i == nch - 1) {
#pragma unroll
                for (int r = 0; r < 16; ++r) {
                    const int kl = (r & 3) + 8 * (r >> 2) + 4 * g;
                    if (kl > c32) s_cur[r] = -1e30f;
                }
            }
            float a0 = fmaxf(fmaxf(s_cur[0], s_cur[1]), fmaxf(s_cur[2], s_cur[3]));
            float a1 = fmaxf(fmaxf(s_cur[4], s_cur[5]), fmaxf(s_cur[6], s_cur[7]));
            float a2 = fmaxf(fmaxf(s_cur[8], s_cur[9]), fmaxf(s_cur[10], s_cur[11]));
            float a3 = fmaxf(fmaxf(s_cur[12], s_cur[13]), fmaxf(s_cur[14], s_cur[15]));
            float pm = fmaxf(fmaxf(a0, a1), fmaxf(a2, a3));
            if (!__all(pm <= m + 8.0f)) {
                float rmax = fmaxf(pm, __shfl_xor(pm, 32, 64));
                const float mn = fmaxf(m, rmax);
                const float alpha = exp2f(m - mn);
#pragma unroll
                for (int r = 0; r < 16; ++r) { o0[r] *= alpha; o1[r] *= alpha; }
                ssum *= alpha;
                m = mn;
            }
            float p[16];
#pragma unroll
            for (int r = 0; r < 16; ++r) p[r] = exp2f(s_cur[r] - m);
            float s0 = (p[0] + p[1]) + (p[2] + p[3]);
            float s1 = (p[4] + p[5]) + (p[6] + p[7]);
            float s2 = (p[8] + p[9]) + (p[10] + p[11]);
            float s3 = (p[12] + p[13]) + (p[14] + p[15]);
            ssum += (s0 + s1) + (s2 + s3);
            unsigned c01 = cvt2(p[0], p[1]), c23 = cvt2(p[2], p[3]);
            unsigned c45 = cvt2(p[4], p[5]), c67 = cvt2(p[6], p[7]);
            pswap(c01, c45); pswap(c23, c67);
            unsigned c89 = cvt2(p[8], p[9]), cab = cvt2(p[10], p[11]);
            unsigned ccd = cvt2(p[12], p[13]), cef = cvt2(p[14], p[15]);
            pswap(c89, ccd); pswap(cab, cef);
            uint4v u0; u0[0] = c01; u0[1] = c23; u0[2] = c45; u0[3] = c67;
            uint4v u1; u1[0] = c89; u1[1] = cab; u1[2] = ccd; u1[3] = cef;
            bf16x8 pb0 = __builtin_bit_cast(bf16x8, u0);
            bf16x8 pb1 = __builtin_bit_cast(bf16x8, u1);
            __builtin_amdgcn_s_setprio(1);
            o0 = MFMA32(vR[0], pb0, o0);
            o0 = MFMA32(vR[1], pb1, o0);
            o1 = MFMA32(vR[2], pb0, o1);
            o1 = MFMA32(vR[3], pb1, o1);
            if (i + 1 < nch) {
                f32x16 t = zero16();
#pragma unroll
                for (int t4 = 0; t4 < 4; ++t4) t = MFMA32(kn[t4], qf[t4], t);
                s_cur = t;
            }
            __builtin_amdgcn_s_setprio(0);
        };

        int i = 0;
        while (i < nch) {
            STEP(k1, i); ++i;
            if (i < nch) { STEP(k0, i); ++i; }
        }
        ssum += __shfl_xor(ssum, 32, 64);

        if (l < 32) { msh[w][l] = m; ssh[w][l] = ssum; }
#pragma unroll
        for (int q4 = 0; q4 < 4; ++q4) {
            const int base = 8 * q4 + 4 * g;
            *(unsigned*)&Osh[w][c32][base]      = cvt2(o0[4 * q4], o0[4 * q4 + 1]);
            *(unsigned*)&Osh[w][c32][base + 2]  = cvt2(o0[4 * q4 + 2], o0[4 * q4 + 3]);
            *(unsigned*)&Osh[w][c32][base + 32] = cvt2(o1[4 * q4], o1[4 * q4 + 1]);
            *(unsigned*)&Osh[w][c32][base + 34] = cvt2(o1[4 * q4 + 2], o1[4 * q4 + 3]);
        }
        __syncthreads();

        if (tid < 512) {
            const int qrow = tid >> 4, e4 = tid & 15;
            float M = -INFINITY;
            float mw[NW];
#pragma unroll
            for (int u = 0; u < NW; ++u) { mw[u] = msh[u][qrow]; M = fmaxf(M, mw[u]); }
            float den = 0.0f;
            float r0 = 0.f, r1 = 0.f, r2 = 0.f, r3 = 0.f;
#pragma unroll
            for (int u = 0; u < NW; ++u) {
                const float scu = exp2f(mw[u] - M);
                den += ssh[u][qrow] * scu;
                const unsigned ua = *(const unsigned*)&Osh[u][qrow][4 * e4];
                const unsigned ub = *(const unsigned*)&Osh[u][qrow][4 * e4 + 2];
                r0 += bflo(ua) * scu;
                r1 += bfhi(ua) * scu;
                r2 += bflo(ub) * scu;
                r3 += bfhi(ub) * scu;
            }
            const float inv = 1.0f / den;
            float4 st;
            st.x = r0 * inv; st.y = r1 * inv; st.z = r2 * inv; st.w = r3 * inv;
            *(float4*)(out + ((size_t)b * T_SEQ + qbase + qrow) * 64 + 4 * e4) = st;
        }
        __syncthreads();
    }
}

// ---------------- launch ----------------
extern "C" void kernel_launch(void* const* d_in, const int* in_sizes, int n_in,
                              void* d_out, int out_size, void* d_ws, size_t ws_size,
                              hipStream_t stream) {
    const float* x  = (const float*)d_in[0];
    const float* Wq = (const float*)d_in[1];
    const float* bq = (const float*)d_in[2];
    const float* Wk = (const float*)d_in[3];
    const float* bk = (const float*)d_in[4];
    const float* Wv = (const float*)d_in[5];
    const float* bv = (const float*)d_in[6];
    float* out = (float*)d_out;

    char* ws = (char*)d_ws;
    unsigned short* Wt3    = (unsigned short*)(ws);                 // 384 KB
    float*          bias_t = (float*)(ws + 393216);                 // 768 B
    unsigned short* qsb    = (unsigned short*)(ws + (1u << 20));    // 2 MB
    unsigned short* ksb    = (unsigned short*)(ws + (3u << 20));    // 2 MB
    unsigned short* vtb    = (unsigned short*)(ws + (5u << 20));    // 2 MB

    prep_w<<<48, 256, 0, stream>>>(Wq, Wk, Wv, bq, bk, bv, Wt3, bias_t);
    proj_kernel<<<256, 768, 0, stream>>>(x, Wt3, bias_t, qsb, ksb, vtb);
    attn_kernel<<<256, 768, 0, stream>>>(qsb, ksb, vtb, out);
}

// Round 16
// 58.807 us; speedup vs baseline: 1.1725x; 1.0440x over previous
//
#include <hip/hip_runtime.h>
#include <hip/hip_bf16.h>

// AttentionHead: B=4, T=4096, D=1024, DA=64, scale = 1/96 folded into q.
// R16 = R13 + ONE change: proj split into 512 blocks x 384 thr (6 waves,
// 32 rows). Two co-resident blocks per CU = two independent barrier
// domains -> while one block drains at s_barrier the other issues.
// (R15's B-dbuf was neutral -> dropped. attn = R13 verbatim.)

#define T_SEQ 4096
#define NW 12   // attention waves per block (3/SIMD; unified-reg cap 170)

using bf16x8 = __bf16 __attribute__((ext_vector_type(8)));
using f32x16 = float __attribute__((ext_vector_type(16)));
using uint4v = unsigned int __attribute__((ext_vector_type(4)));

static constexpr float QSCALE = 1.4426950408889634f / 96.0f;

__device__ __forceinline__ unsigned short bf1(float v) {
    unsigned u = __builtin_bit_cast(unsigned, v);
    u += 0x7FFFu + ((u >> 16) & 1u);
    return (unsigned short)(u >> 16);
}
__device__ __forceinline__ unsigned cvt2(float lo, float hi) {
    unsigned r;
    asm("v_cvt_pk_bf16_f32 %0, %1, %2" : "=v"(r) : "v"(lo), "v"(hi));
    return r;
}
// v_permlane32_swap: ONLY safe when a,b hold DISTINCT values (see R8 note).
__device__ __forceinline__ void pswap(unsigned& a, unsigned& b) {
    asm volatile("v_permlane32_swap_b32 %0, %1" : "+v"(a), "+v"(b));
}
__device__ __forceinline__ float bflo(unsigned u) {
    return __builtin_bit_cast(float, u << 16);
}
__device__ __forceinline__ float bfhi(unsigned u) {
    return __builtin_bit_cast(float, u & 0xFFFF0000u);
}
__device__ __forceinline__ f32x16 zero16() {
    f32x16 z;
#pragma unroll
    for (int i = 0; i < 16; ++i) z[i] = 0.0f;
    return z;
}
#define MFMA32(a, b, c) __builtin_amdgcn_mfma_f32_32x32x16_bf16(a, b, c, 0, 0, 0)

// ---------------- kernel 1: W -> Wt3 frag-linear bf16 ----------------
// Wt3 flat: ((kt*6 + ct)*4 + kk)*512 + lane*8 + e
//   where col cg = ct*32 + (lane&31), k = kt*64 + kk*16 + (lane>>5)*8 + e.
__global__ __launch_bounds__(256) void prep_w(
        const float* __restrict__ Wq, const float* __restrict__ Wk,
        const float* __restrict__ Wv, const float* __restrict__ bq,
        const float* __restrict__ bk, const float* __restrict__ bv,
        unsigned short* __restrict__ Wt3, float* __restrict__ bias_t) {
    __shared__ float tile[64][65];
    const int tid = threadIdx.x;
    const int m = blockIdx.x >> 4, kt = blockIdx.x & 15, d0 = kt * 64;
    const float* W = (m == 0) ? Wq : (m == 1) ? Wk : Wv;
    const int a = tid & 63, r4 = tid >> 6;
#pragma unroll
    for (int j = 0; j < 16; ++j) {
        const int rr = r4 + 4 * j;
        tile[rr][a] = W[(size_t)(d0 + rr) * 64 + a];
    }
    __syncthreads();
    const float scl = (m == 0) ? QSCALE : 1.0f;
    const int dc = tid & 63, ar = tid >> 6;
#pragma unroll
    for (int j = 0; j < 16; ++j) {
        const int aa = ar + 4 * j;
        const int cg = m * 64 + aa;
        const size_t addr =
            ((size_t)(kt * 6 + (cg >> 5)) * 4 + (dc >> 4)) * 512 +
            ((cg & 31) + 32 * ((dc >> 3) & 1)) * 8 + (dc & 7);
        Wt3[addr] = bf1(tile[dc][aa] * scl);
    }
    if (kt == 0 && tid < 64) {
        const float* bb = (m == 0) ? bq : (m == 1) ? bk : bv;
        bias_t[m * 64 + tid] = bb[tid] * scl;
    }
}

// ---------------- kernel 2: QKV projection (v6: 2 blocks/CU) ----------
// 512 blocks x 384 thr = 6 waves (ct 0..5). 32 rows/block, full K=1024,
// 16 stages, 3-deep x prefetch, pad-68 A-tile, frag-linear B.
// Two blocks co-resident per CU -> independent barrier domains overlap.
__global__ __launch_bounds__(384, 3) void proj_kernel(
        const float* __restrict__ x, const unsigned short* __restrict__ Wt3,
        const float* __restrict__ bias_t, unsigned short* __restrict__ qs,
        unsigned short* __restrict__ ksf, unsigned short* __restrict__ vtf) {
    __shared__ unsigned short Ald[2][32 * 68];   // 2 x 4.25 KB bf16

    const int tid = threadIdx.x;
    const int w = tid >> 6, l = tid & 63, g = l >> 5, c32 = l & 31;
    const int ct = w;                     // 6 waves = 6 col-tiles
    const int rowbase = blockIdx.x * 32;

    // staging: 512 float4/stage over 384 thr (tid<128 carry a 2nd slice)
    const int r0 = tid >> 4, k40 = tid & 15;        // rows 0..23
    const int r1 = (tid + 384) >> 4, k41 = tid & 15; // rows 24..31 (tid<128)
    const bool haveB = (tid < 128);
    const float* xb0 = x + (size_t)(rowbase + r0) * 1024 + k40 * 4;
    const float* xb1 = x + (size_t)(rowbase + r1) * 1024 + k41 * 4;
    const int wo0 = r0 * 68 + k40 * 4;
    const int wo1 = r1 * 68 + k41 * 4;

    const unsigned short* Wb = Wt3 + (size_t)(ct * 4) * 512 + l * 8;
    const int aro = c32 * 68;

    f32x16 acc = zero16();
    float4 ra[3], rb[3];   // 3-slot static rotation

    {
        float4 a0 = *(const float4*)(xb0);
        float4 b0;
        if (haveB) b0 = *(const float4*)(xb1);
        *(uint2*)(Ald[0] + wo0) = make_uint2(cvt2(a0.x, a0.y), cvt2(a0.z, a0.w));
        if (haveB)
            *(uint2*)(Ald[0] + wo1) = make_uint2(cvt2(b0.x, b0.y), cvt2(b0.z, b0.w));
    }
#pragma unroll
    for (int s = 1; s <= 3; ++s) {
        ra[s % 3] = *(const float4*)(xb0 + s * 64);
        if (haveB) rb[s % 3] = *(const float4*)(xb1 + s * 64);
    }
    asm volatile("s_waitcnt lgkmcnt(0)" ::: "memory");
    __builtin_amdgcn_s_barrier();
    __builtin_amdgcn_sched_barrier(0);

#pragma unroll
    for (int kt = 0; kt < 16; ++kt) {
        const unsigned short* A = Ald[kt & 1];
        const unsigned short* Wkt = Wb + (size_t)kt * 12288;
        bf16x8 b0 = *(const bf16x8*)(Wkt);
        bf16x8 b1 = *(const bf16x8*)(Wkt + 512);
        bf16x8 b2 = *(const bf16x8*)(Wkt + 1024);
        bf16x8 b3 = *(const bf16x8*)(Wkt + 1536);
        if (kt < 15) {
            float4 a = ra[(kt + 1) % 3];
            *(uint2*)(Ald[(kt + 1) & 1] + wo0) =
                make_uint2(cvt2(a.x, a.y), cvt2(a.z, a.w));
            if (haveB) {
                float4 b4 = rb[(kt + 1) % 3];
                *(uint2*)(Ald[(kt + 1) & 1] + wo1) =
                    make_uint2(cvt2(b4.x, b4.y), cvt2(b4.z, b4.w));
            }
        }
        if (kt < 12) {
            ra[(kt + 4) % 3] = *(const float4*)(xb0 + (kt + 4) * 64);
            if (haveB) rb[(kt + 4) % 3] = *(const float4*)(xb1 + (kt + 4) * 64);
        }
        {
            bf16x8 a0 = *(const bf16x8*)(A + aro + (0 + g) * 8);
            bf16x8 a1 = *(const bf16x8*)(A + aro + (2 + g) * 8);
            bf16x8 a2 = *(const bf16x8*)(A + aro + (4 + g) * 8);
            bf16x8 a3 = *(const bf16x8*)(A + aro + (6 + g) * 8);
            acc = MFMA32(a0, b0, acc);
            acc = MFMA32(a1, b1, acc);
            acc = MFMA32(a2, b2, acc);
            acc = MFMA32(a3, b3, acc);
        }
        asm volatile("s_waitcnt lgkmcnt(0)" ::: "memory");
        __builtin_amdgcn_s_barrier();
        __builtin_amdgcn_sched_barrier(0);
    }

    // epilogue
    const int cg = ct * 32 + c32;
    const float bias = bias_t[cg];
    const int mat = cg >> 6, cm = cg & 63;
    if (mat == 2) {
#pragma unroll
        for (int q4 = 0; q4 < 4; ++q4) {
            const int rowg = rowbase + 8 * q4 + 4 * g;
            const int b = rowg >> 12, tl = rowg & (T_SEQ - 1);
            const int ch = tl >> 5;
            const int f = (cm >> 5) * 2 + (q4 >> 1);
            const int lane = (cm & 31) + 32 * (q4 & 1);
            unsigned lo = cvt2(acc[4 * q4 + 0] + bias, acc[4 * q4 + 1] + bias);
            unsigned hi = cvt2(acc[4 * q4 + 2] + bias, acc[4 * q4 + 3] + bias);
            *(uint2*)(vtf + ((size_t)b * 128 + ch) * 2048 + f * 512 +
                      lane * 8 + 4 * g) = make_uint2(lo, hi);
        }
    } else if (mat == 1) {
#pragma unroll
        for (int r = 0; r < 16; ++r) {
            const int rowg = rowbase + (r & 3) + 8 * (r >> 2) + 4 * g;
            const int b = rowg >> 12, tl = rowg & (T_SEQ - 1);
            ksf[((size_t)b * 128 + (tl >> 5)) * 2048 + (cm >> 4) * 512 +
                ((tl & 31) + 32 * ((cm >> 3) & 1)) * 8 + (cm & 7)] =
                bf1(acc[r] + bias);
        }
    } else {
#pragma unroll
        for (int r = 0; r < 16; ++r) {
            const int rowg = rowbase + (r & 3) + 8 * (r >> 2) + 4 * g;
            qs[(size_t)rowg * 64 + cm] = bf1(acc[r] + bias);
        }
    }
}

// ---------------- kernel 3: causal flash attention (R13 verbatim) --------
__global__ __launch_bounds__(768, 3) void attn_kernel(
        const unsigned short* __restrict__ qs, const unsigned short* __restrict__ ksf,
        const unsigned short* __restrict__ vtf, float* __restrict__ out) {
    __shared__ unsigned short Osh[NW][32][66];
    __shared__ float msh[NW][32];
    __shared__ float ssh[NW][32];

    const int tid = threadIdx.x;
    const int w = tid >> 6, l = tid & 63, g = l >> 5, c32 = l & 31;
    const int b = blockIdx.x & 3;
    const int pid = blockIdx.x >> 2;

    for (int tt = 0; tt < 2; ++tt) {
        const int jt = tt ? pid : 127 - pid;
        const int qbase = jt * 32;

        const unsigned short* qp =
            qs + ((size_t)b * T_SEQ + qbase + c32) * 64 + g * 8;
        bf16x8 qf[4];
#pragma unroll
        for (int t = 0; t < 4; ++t) qf[t] = *(const bf16x8*)(qp + 16 * t);

        const unsigned short* pKc = ksf + ((size_t)b * 128 + w) * 2048 + l * 8;
        const unsigned short* pVc = vtf + ((size_t)b * 128 + w) * 2048 + l * 8;

        auto loadK = [&](bf16x8(&kf)[4]) {
#pragma unroll
            for (int t = 0; t < 4; ++t)
                kf[t] = *(const bf16x8*)(pKc + t * 512);
            pKc += NW * 2048;
        };
        auto loadV = [&](bf16x8(&vf)[4]) {
#pragma unroll
            for (int f = 0; f < 4; ++f)
                vf[f] = *(const bf16x8*)(pVc + f * 512);
            pVc += NW * 2048;
        };

        const int nch = (jt >= w) ? (jt - w) / NW + 1 : 0;
        const bool hasDiag = (jt >= w) && ((jt - w) % NW == 0);
        float m = -INFINITY, ssum = 0.0f;
        f32x16 o0 = zero16(), o1 = zero16();
        f32x16 s_cur;
        bf16x8 k0[4], k1[4], vR[4];

        if (nch > 0) {
            loadK(k0);
            f32x16 t = zero16();
#pragma unroll
            for (int t4 = 0; t4 < 4; ++t4) t = MFMA32(k0[t4], qf[t4], t);
            s_cur = t;
        }

        auto STEP = [&](bf16x8(&kn)[4], int i) {
            loadV(vR);
            if (i + 1 < nch) loadK(kn);
            if (hasDiag && i == nch - 1) {
#pragma unroll
                for (int r = 0; r < 16; ++r) {
                    const int kl = (r & 3) + 8 * (r >> 2) + 4 * g;
                    if (kl > c32) s_cur[r] = -1e30f;
                }
            }
            float a0 = fmaxf(fmaxf(s_cur[0], s_cur[1]), fmaxf(s_cur[2], s_cur[3]));
            float a1 = fmaxf(fmaxf(s_cur[4], s_cur[5]), fmaxf(s_cur[6], s_cur[7]));
            float a2 = fmaxf(fmaxf(s_cur[8], s_cur[9]), fmaxf(s_cur[10], s_cur[11]));
            float a3 = fmaxf(fmaxf(s_cur[12], s_cur[13]), fmaxf(s_cur[14], s_cur[15]));
            float pm = fmaxf(fmaxf(a0, a1), fmaxf(a2, a3));
            if (!__all(pm <= m + 8.0f)) {
                float rmax = fmaxf(pm, __shfl_xor(pm, 32, 64));
                const float mn = fmaxf(m, rmax);
                const float alpha = exp2f(m - mn);
#pragma unroll
                for (int r = 0; r < 16; ++r) { o0[r] *= alpha; o1[r] *= alpha; }
                ssum *= alpha;
                m = mn;
            }
            float p[16];
#pragma unroll
            for (int r = 0; r < 16; ++r) p[r] = exp2f(s_cur[r] - m);
            float s0 = (p[0] + p[1]) + (p[2] + p[3]);
            float s1 = (p[4] + p[5]) + (p[6] + p[7]);
            float s2 = (p[8] + p[9]) + (p[10] + p[11]);
            float s3 = (p[12] + p[13]) + (p[14] + p[15]);
            ssum += (s0 + s1) + (s2 + s3);
            unsigned c01 = cvt2(p[0], p[1]), c23 = cvt2(p[2], p[3]);
            unsigned c45 = cvt2(p[4], p[5]), c67 = cvt2(p[6], p[7]);
            pswap(c01, c45); pswap(c23, c67);
            unsigned c89 = cvt2(p[8], p[9]), cab = cvt2(p[10], p[11]);
            unsigned ccd = cvt2(p[12], p[13]), cef = cvt2(p[14], p[15]);
            pswap(c89, ccd); pswap(cab, cef);
            uint4v u0; u0[0] = c01; u0[1] = c23; u0[2] = c45; u0[3] = c67;
            uint4v u1; u1[0] = c89; u1[1] = cab; u1[2] = ccd; u1[3] = cef;
            bf16x8 pb0 = __builtin_bit_cast(bf16x8, u0);
            bf16x8 pb1 = __builtin_bit_cast(bf16x8, u1);
            __builtin_amdgcn_s_setprio(1);
            o0 = MFMA32(vR[0], pb0, o0);
            o0 = MFMA32(vR[1], pb1, o0);
            o1 = MFMA32(vR[2], pb0, o1);
            o1 = MFMA32(vR[3], pb1, o1);
            if (i + 1 < nch) {
                f32x16 t = zero16();
#pragma unroll
                for (int t4 = 0; t4 < 4; ++t4) t = MFMA32(kn[t4], qf[t4], t);
                s_cur = t;
            }
            __builtin_amdgcn_s_setprio(0);
        };

        int i = 0;
        while (i < nch) {
            STEP(k1, i); ++i;
            if (i < nch) { STEP(k0, i); ++i; }
        }
        ssum += __shfl_xor(ssum, 32, 64);

        if (l < 32) { msh[w][l] = m; ssh[w][l] = ssum; }
#pragma unroll
        for (int q4 = 0; q4 < 4; ++q4) {
            const int base = 8 * q4 + 4 * g;
            *(unsigned*)&Osh[w][c32][base]      = cvt2(o0[4 * q4], o0[4 * q4 + 1]);
            *(unsigned*)&Osh[w][c32][base + 2]  = cvt2(o0[4 * q4 + 2], o0[4 * q4 + 3]);
            *(unsigned*)&Osh[w][c32][base + 32] = cvt2(o1[4 * q4], o1[4 * q4 + 1]);
            *(unsigned*)&Osh[w][c32][base + 34] = cvt2(o1[4 * q4 + 2], o1[4 * q4 + 3]);
        }
        __syncthreads();

        if (tid < 512) {
            const int qrow = tid >> 4, e4 = tid & 15;
            float M = -INFINITY;
            float mw[NW];
#pragma unroll
            for (int u = 0; u < NW; ++u) { mw[u] = msh[u][qrow]; M = fmaxf(M, mw[u]); }
            float den = 0.0f;
            float r0 = 0.f, r1 = 0.f, r2 = 0.f, r3 = 0.f;
#pragma unroll
            for (int u = 0; u < NW; ++u) {
                const float scu = exp2f(mw[u] - M);
                den += ssh[u][qrow] * scu;
                const unsigned ua = *(const unsigned*)&Osh[u][qrow][4 * e4];
                const unsigned ub = *(const unsigned*)&Osh[u][qrow][4 * e4 + 2];
                r0 += bflo(ua) * scu;
                r1 += bfhi(ua) * scu;
                r2 += bflo(ub) * scu;
                r3 += bfhi(ub) * scu;
            }
            const float inv = 1.0f / den;
            float4 st;
            st.x = r0 * inv; st.y = r1 * inv; st.z = r2 * inv; st.w = r3 * inv;
            *(float4*)(out + ((size_t)b * T_SEQ + qbase + qrow) * 64 + 4 * e4) = st;
        }
        __syncthreads();
    }
}

// ---------------- launch ----------------
extern "C" void kernel_launch(void* const* d_in, const int* in_sizes, int n_in,
                              void* d_out, int out_size, void* d_ws, size_t ws_size,
                              hipStream_t stream) {
    const float* x  = (const float*)d_in[0];
    const float* Wq = (const float*)d_in[1];
    const float* bq = (const float*)d_in[2];
    const float* Wk = (const float*)d_in[3];
    const float* bk = (const float*)d_in[4];
    const float* Wv = (const float*)d_in[5];
    const float* bv = (const float*)d_in[6];
    float* out = (float*)d_out;

    char* ws = (char*)d_ws;
    unsigned short* Wt3    = (unsigned short*)(ws);                 // 384 KB
    float*          bias_t = (float*)(ws + 393216);                 // 768 B
    unsigned short* qsb    = (unsigned short*)(ws + (1u << 20));    // 2 MB
    unsigned short* ksb    = (unsigned short*)(ws + (3u << 20));    // 2 MB
    unsigned short* vtb    = (unsigned short*)(ws + (5u << 20));    // 2 MB

    prep_w<<<48, 256, 0, stream>>>(Wq, Wk, Wv, bq, bk, bv, Wt3, bias_t);
    proj_kernel<<<512, 384, 0, stream>>>(x, Wt3, bias_t, qsb, ksb, vtb);
    attn_kernel<<<256, 768, 0, stream>>>(qsb, ksb, vtb, out);
}

// Round 17
// 50.165 us; speedup vs baseline: 1.3745x; 1.1723x over previous
//
#include <hip/hip_runtime.h>
#include <hip/hip_bf16.h>

// AttentionHead: B=4, T=4096, D=1024, DA=64, scale = 1/96 folded into q.
// R17 = R16 + ONE change: proj staging via global_load_lds DMA (m97-style).
// x goes fp32 -> LDS by DMA (8 width-16 calls/stage, wave-distributed),
// bf16 conversion AFTER ds_read. DMA dest must be linear, so the 32-way
// bank conflict on 256B rows is fixed by pre-swizzling the GLOBAL source:
// LDS[row][b] = x[row][b ^ (row&7)], read back with the same XOR (4-way).
// One __syncthreads per stage (drains next-buffer DMA). attn/prep = R16.

#define T_SEQ 4096
#define NW 12   // attention waves per block (3/SIMD; unified-reg cap 170)

using bf16x8 = __bf16 __attribute__((ext_vector_type(8)));
using f32x16 = float __attribute__((ext_vector_type(16)));
using uint4v = unsigned int __attribute__((ext_vector_type(4)));

static constexpr float QSCALE = 1.4426950408889634f / 96.0f;

__device__ __forceinline__ unsigned short bf1(float v) {
    unsigned u = __builtin_bit_cast(unsigned, v);
    u += 0x7FFFu + ((u >> 16) & 1u);
    return (unsigned short)(u >> 16);
}
__device__ __forceinline__ unsigned cvt2(float lo, float hi) {
    unsigned r;
    asm("v_cvt_pk_bf16_f32 %0, %1, %2" : "=v"(r) : "v"(lo), "v"(hi));
    return r;
}
// v_permlane32_swap: ONLY safe when a,b hold DISTINCT values (see R8 note).
__device__ __forceinline__ void pswap(unsigned& a, unsigned& b) {
    asm volatile("v_permlane32_swap_b32 %0, %1" : "+v"(a), "+v"(b));
}
__device__ __forceinline__ float bflo(unsigned u) {
    return __builtin_bit_cast(float, u << 16);
}
__device__ __forceinline__ float bfhi(unsigned u) {
    return __builtin_bit_cast(float, u & 0xFFFF0000u);
}
__device__ __forceinline__ f32x16 zero16() {
    f32x16 z;
#pragma unroll
    for (int i = 0; i < 16; ++i) z[i] = 0.0f;
    return z;
}
#define MFMA32(a, b, c) __builtin_amdgcn_mfma_f32_32x32x16_bf16(a, b, c, 0, 0, 0)

// async global -> LDS, 16B per lane (dest = wave-uniform base + lane*16)
__device__ __forceinline__ void gload_lds16(const float* g, float* l) {
    __builtin_amdgcn_global_load_lds(
        (const __attribute__((address_space(1))) float*)g,
        (__attribute__((address_space(3))) float*)l, 16, 0, 0);
}

// ---------------- kernel 1: W -> Wt3 frag-linear bf16 ----------------
// Wt3 flat: ((kt*6 + ct)*4 + kk)*512 + lane*8 + e
//   where col cg = ct*32 + (lane&31), k = kt*64 + kk*16 + (lane>>5)*8 + e.
__global__ __launch_bounds__(256) void prep_w(
        const float* __restrict__ Wq, const float* __restrict__ Wk,
        const float* __restrict__ Wv, const float* __restrict__ bq,
        const float* __restrict__ bk, const float* __restrict__ bv,
        unsigned short* __restrict__ Wt3, float* __restrict__ bias_t) {
    __shared__ float tile[64][65];
    const int tid = threadIdx.x;
    const int m = blockIdx.x >> 4, kt = blockIdx.x & 15, d0 = kt * 64;
    const float* W = (m == 0) ? Wq : (m == 1) ? Wk : Wv;
    const int a = tid & 63, r4 = tid >> 6;
#pragma unroll
    for (int j = 0; j < 16; ++j) {
        const int rr = r4 + 4 * j;
        tile[rr][a] = W[(size_t)(d0 + rr) * 64 + a];
    }
    __syncthreads();
    const float scl = (m == 0) ? QSCALE : 1.0f;
    const int dc = tid & 63, ar = tid >> 6;
#pragma unroll
    for (int j = 0; j < 16; ++j) {
        const int aa = ar + 4 * j;
        const int cg = m * 64 + aa;
        const size_t addr =
            ((size_t)(kt * 6 + (cg >> 5)) * 4 + (dc >> 4)) * 512 +
            ((cg & 31) + 32 * ((dc >> 3) & 1)) * 8 + (dc & 7);
        Wt3[addr] = bf1(tile[dc][aa] * scl);
    }
    if (kt == 0 && tid < 64) {
        const float* bb = (m == 0) ? bq : (m == 1) ? bk : bv;
        bias_t[m * 64 + tid] = bb[tid] * scl;
    }
}

// ---------------- kernel 2: QKV projection (v7: global_load_lds) ----------
// 512 blocks x 384 thr = 6 waves (ct 0..5). 32 rows/block, full K=1024,
// 16 stages. x staged fp32 via DMA with source-swizzled 16B blocks;
// bf16 conversion post-ds_read; frag-linear B; 1 barrier/stage.
__global__ __launch_bounds__(384, 3) void proj_kernel(
        const float* __restrict__ x, const unsigned short* __restrict__ Wt3,
        const float* __restrict__ bias_t, unsigned short* __restrict__ qs,
        unsigned short* __restrict__ ksf, unsigned short* __restrict__ vtf) {
    __shared__ float Ald[2][2048];   // [buf][32 rows x 64 f32] = 2 x 8 KB

    const int tid = threadIdx.x;
    const int w = tid >> 6, l = tid & 63, g = l >> 5, c32 = l & 31;
    const int ct = w;                     // 6 waves = 6 col-tiles
    const int rowbase = blockIdx.x * 32;

    // DMA call j covers rows 4j..4j+3 (1 KB). wave w: call w; waves 0,1
    // also take calls 6,7. lane l: row = 4j+(l>>4), dest blk = l&15,
    // SOURCE blk = (l&15) ^ (row&7)  [involution; read applies same XOR].
    const int j1 = w;
    const int row1 = 4 * j1 + (l >> 4);
    const float* gp1 = x + (size_t)(rowbase + row1) * 1024 +
                       (((l & 15) ^ (row1 & 7)) << 2);
    const bool has2 = (w < 2);
    const int j2 = 6 + w;
    const int row2 = 4 * j2 + (l >> 4);
    const float* gp2 = x + (size_t)(rowbase + row2) * 1024 +
                       (((l & 15) ^ (row2 & 7)) << 2);

    const unsigned short* Wb = Wt3 + (size_t)(ct * 4) * 512 + l * 8;

    f32x16 acc = zero16();

    // prologue: DMA stage 0 -> buf 0
    gload_lds16(gp1, &Ald[0][j1 * 256]);
    if (has2) gload_lds16(gp2, &Ald[0][j2 * 256]);
    __syncthreads();

#pragma unroll
    for (int kt = 0; kt < 16; ++kt) {
        // (1) DMA next stage into the other buffer (readers of it finished
        //     at the previous barrier; this barrier drains it for kt+1)
        if (kt < 15) {
            gload_lds16(gp1 + (kt + 1) * 64, &Ald[(kt + 1) & 1][j1 * 256]);
            if (has2)
                gload_lds16(gp2 + (kt + 1) * 64, &Ald[(kt + 1) & 1][j2 * 256]);
        }
        // (2) ds_read fp32 frags (swizzled) + convert + MFMA
        const float* A = Ald[kt & 1];
        const unsigned short* Wkt = Wb + (size_t)kt * 12288;
#pragma unroll
        for (int kk = 0; kk < 4; ++kk) {
            const int blk = kk * 4 + g * 2;
            float4 f0 = *(const float4*)(A + c32 * 64 + ((blk ^ (c32 & 7)) << 2));
            float4 f1 = *(const float4*)(A + c32 * 64 + (((blk + 1) ^ (c32 & 7)) << 2));
            uint4v ua;
            ua[0] = cvt2(f0.x, f0.y); ua[1] = cvt2(f0.z, f0.w);
            ua[2] = cvt2(f1.x, f1.y); ua[3] = cvt2(f1.z, f1.w);
            bf16x8 af = __builtin_bit_cast(bf16x8, ua);
            bf16x8 bfr = *(const bf16x8*)(Wkt + kk * 512);
            acc = MFMA32(af, bfr, acc);
        }
        __syncthreads();   // drains DMA (vmcnt) + orders buffer reuse
    }

    // epilogue (unchanged)
    const int cg = ct * 32 + c32;
    const float bias = bias_t[cg];
    const int mat = cg >> 6, cm = cg & 63;
    if (mat == 2) {
#pragma unroll
        for (int q4 = 0; q4 < 4; ++q4) {
            const int rowg = rowbase + 8 * q4 + 4 * g;
            const int b = rowg >> 12, tl = rowg & (T_SEQ - 1);
            const int ch = tl >> 5;
            const int f = (cm >> 5) * 2 + (q4 >> 1);
            const int lane = (cm & 31) + 32 * (q4 & 1);
            unsigned lo = cvt2(acc[4 * q4 + 0] + bias, acc[4 * q4 + 1] + bias);
            unsigned hi = cvt2(acc[4 * q4 + 2] + bias, acc[4 * q4 + 3] + bias);
            *(uint2*)(vtf + ((size_t)b * 128 + ch) * 2048 + f * 512 +
                      lane * 8 + 4 * g) = make_uint2(lo, hi);
        }
    } else if (mat == 1) {
#pragma unroll
        for (int r = 0; r < 16; ++r) {
            const int rowg = rowbase + (r & 3) + 8 * (r >> 2) + 4 * g;
            const int b = rowg >> 12, tl = rowg & (T_SEQ - 1);
            ksf[((size_t)b * 128 + (tl >> 5)) * 2048 + (cm >> 4) * 512 +
                ((tl & 31) + 32 * ((cm >> 3) & 1)) * 8 + (cm & 7)] =
                bf1(acc[r] + bias);
        }
    } else {
#pragma unroll
        for (int r = 0; r < 16; ++r) {
            const int rowg = rowbase + (r & 3) + 8 * (r >> 2) + 4 * g;
            qs[(size_t)rowg * 64 + cm] = bf1(acc[r] + bias);
        }
    }
}

// ---------------- kernel 3: causal flash attention (R13 verbatim) --------
__global__ __launch_bounds__(768, 3) void attn_kernel(
        const unsigned short* __restrict__ qs, const unsigned short* __restrict__ ksf,
        const unsigned short* __restrict__ vtf, float* __restrict__ out) {
    __shared__ unsigned short Osh[NW][32][66];
    __shared__ float msh[NW][32];
    __shared__ float ssh[NW][32];

    const int tid = threadIdx.x;
    const int w = tid >> 6, l = tid & 63, g = l >> 5, c32 = l & 31;
    const int b = blockIdx.x & 3;
    const int pid = blockIdx.x >> 2;

    for (int tt = 0; tt < 2; ++tt) {
        const int jt = tt ? pid : 127 - pid;
        const int qbase = jt * 32;

        const unsigned short* qp =
            qs + ((size_t)b * T_SEQ + qbase + c32) * 64 + g * 8;
        bf16x8 qf[4];
#pragma unroll
        for (int t = 0; t < 4; ++t) qf[t] = *(const bf16x8*)(qp + 16 * t);

        const unsigned short* pKc = ksf + ((size_t)b * 128 + w) * 2048 + l * 8;
        const unsigned short* pVc = vtf + ((size_t)b * 128 + w) * 2048 + l * 8;

        auto loadK = [&](bf16x8(&kf)[4]) {
#pragma unroll
            for (int t = 0; t < 4; ++t)
                kf[t] = *(const bf16x8*)(pKc + t * 512);
            pKc += NW * 2048;
        };
        auto loadV = [&](bf16x8(&vf)[4]) {
#pragma unroll
            for (int f = 0; f < 4; ++f)
                vf[f] = *(const bf16x8*)(pVc + f * 512);
            pVc += NW * 2048;
        };

        const int nch = (jt >= w) ? (jt - w) / NW + 1 : 0;
        const bool hasDiag = (jt >= w) && ((jt - w) % NW == 0);
        float m = -INFINITY, ssum = 0.0f;
        f32x16 o0 = zero16(), o1 = zero16();
        f32x16 s_cur;
        bf16x8 k0[4], k1[4], vR[4];

        if (nch > 0) {
            loadK(k0);
            f32x16 t = zero16();
#pragma unroll
            for (int t4 = 0; t4 < 4; ++t4) t = MFMA32(k0[t4], qf[t4], t);
            s_cur = t;
        }

        auto STEP = [&](bf16x8(&kn)[4], int i) {
            loadV(vR);
            if (i + 1 < nch) loadK(kn);
            if (hasDiag && i == nch - 1) {
#pragma unroll
                for (int r = 0; r < 16; ++r) {
                    const int kl = (r & 3) + 8 * (r >> 2) + 4 * g;
                    if (kl > c32) s_cur[r] = -1e30f;
                }
            }
            float a0 = fmaxf(fmaxf(s_cur[0], s_cur[1]), fmaxf(s_cur[2], s_cur[3]));
            float a1 = fmaxf(fmaxf(s_cur[4], s_cur[5]), fmaxf(s_cur[6], s_cur[7]));
            float a2 = fmaxf(fmaxf(s_cur[8], s_cur[9]), fmaxf(s_cur[10], s_cur[11]));
            float a3 = fmaxf(fmaxf(s_cur[12], s_cur[13]), fmaxf(s_cur[14], s_cur[15]));
            float pm = fmaxf(fmaxf(a0, a1), fmaxf(a2, a3));
            if (!__all(pm <= m + 8.0f)) {
                float rmax = fmaxf(pm, __shfl_xor(pm, 32, 64));
                const float mn = fmaxf(m, rmax);
                const float alpha = exp2f(m - mn);
#pragma unroll
                for (int r = 0; r < 16; ++r) { o0[r] *= alpha; o1[r] *= alpha; }
                ssum *= alpha;
                m = mn;
            }
            float p[16];
#pragma unroll
            for (int r = 0; r < 16; ++r) p[r] = exp2f(s_cur[r] - m);
            float s0 = (p[0] + p[1]) + (p[2] + p[3]);
            float s1 = (p[4] + p[5]) + (p[6] + p[7]);
            float s2 = (p[8] + p[9]) + (p[10] + p[11]);
            float s3 = (p[12] + p[13]) + (p[14] + p[15]);
            ssum += (s0 + s1) + (s2 + s3);
            unsigned c01 = cvt2(p[0], p[1]), c23 = cvt2(p[2], p[3]);
            unsigned c45 = cvt2(p[4], p[5]), c67 = cvt2(p[6], p[7]);
            pswap(c01, c45); pswap(c23, c67);
            unsigned c89 = cvt2(p[8], p[9]), cab = cvt2(p[10], p[11]);
            unsigned ccd = cvt2(p[12], p[13]), cef = cvt2(p[14], p[15]);
            pswap(c89, ccd); pswap(cab, cef);
            uint4v u0; u0[0] = c01; u0[1] = c23; u0[2] = c45; u0[3] = c67;
            uint4v u1; u1[0] = c89; u1[1] = cab; u1[2] = ccd; u1[3] = cef;
            bf16x8 pb0 = __builtin_bit_cast(bf16x8, u0);
            bf16x8 pb1 = __builtin_bit_cast(bf16x8, u1);
            __builtin_amdgcn_s_setprio(1);
            o0 = MFMA32(vR[0], pb0, o0);
            o0 = MFMA32(vR[1], pb1, o0);
            o1 = MFMA32(vR[2], pb0, o1);
            o1 = MFMA32(vR[3], pb1, o1);
            if (i + 1 < nch) {
                f32x16 t = zero16();
#pragma unroll
                for (int t4 = 0; t4 < 4; ++t4) t = MFMA32(kn[t4], qf[t4], t);
                s_cur = t;
            }
            __builtin_amdgcn_s_setprio(0);
        };

        int i = 0;
        while (i < nch) {
            STEP(k1, i); ++i;
            if (i < nch) { STEP(k0, i); ++i; }
        }
        ssum += __shfl_xor(ssum, 32, 64);

        if (l < 32) { msh[w][l] = m; ssh[w][l] = ssum; }
#pragma unroll
        for (int q4 = 0; q4 < 4; ++q4) {
            const int base = 8 * q4 + 4 * g;
            *(unsigned*)&Osh[w][c32][base]      = cvt2(o0[4 * q4], o0[4 * q4 + 1]);
            *(unsigned*)&Osh[w][c32][base + 2]  = cvt2(o0[4 * q4 + 2], o0[4 * q4 + 3]);
            *(unsigned*)&Osh[w][c32][base + 32] = cvt2(o1[4 * q4], o1[4 * q4 + 1]);
            *(unsigned*)&Osh[w][c32][base + 34] = cvt2(o1[4 * q4 + 2], o1[4 * q4 + 3]);
        }
        __syncthreads();

        if (tid < 512) {
            const int qrow = tid >> 4, e4 = tid & 15;
            float M = -INFINITY;
            float mw[NW];
#pragma unroll
            for (int u = 0; u < NW; ++u) { mw[u] = msh[u][qrow]; M = fmaxf(M, mw[u]); }
            float den = 0.0f;
            float r0 = 0.f, r1 = 0.f, r2 = 0.f, r3 = 0.f;
#pragma unroll
            for (int u = 0; u < NW; ++u) {
                const float scu = exp2f(mw[u] - M);
                den += ssh[u][qrow] * scu;
                const unsigned ua = *(const unsigned*)&Osh[u][qrow][4 * e4];
                const unsigned ub = *(const unsigned*)&Osh[u][qrow][4 * e4 + 2];
                r0 += bflo(ua) * scu;
                r1 += bfhi(ua) * scu;
                r2 += bflo(ub) * scu;
                r3 += bfhi(ub) * scu;
            }
            const float inv = 1.0f / den;
            float4 st;
            st.x = r0 * inv; st.y = r1 * inv; st.z = r2 * inv; st.w = r3 * inv;
            *(float4*)(out + ((size_t)b * T_SEQ + qbase + qrow) * 64 + 4 * e4) = st;
        }
        __syncthreads();
    }
}

// ---------------- launch ----------------
extern "C" void kernel_launch(void* const* d_in, const int* in_sizes, int n_in,
                              void* d_out, int out_size, void* d_ws, size_t ws_size,
                              hipStream_t stream) {
    const float* x  = (const float*)d_in[0];
    const float* Wq = (const float*)d_in[1];
    const float* bq = (const float*)d_in[2];
    const float* Wk = (const float*)d_in[3];
    const float* bk = (const float*)d_in[4];
    const float* Wv = (const float*)d_in[5];
    const float* bv = (const float*)d_in[6];
    float* out = (float*)d_out;

    char* ws = (char*)d_ws;
    unsigned short* Wt3    = (unsigned short*)(ws);                 // 384 KB
    float*          bias_t = (float*)(ws + 393216);                 // 768 B
    unsigned short* qsb    = (unsigned short*)(ws + (1u << 20));    // 2 MB
    unsigned short* ksb    = (unsigned short*)(ws + (3u << 20));    // 2 MB
    unsigned short* vtb    = (unsigned short*)(ws + (5u << 20));    // 2 MB

    prep_w<<<48, 256, 0, stream>>>(Wq, Wk, Wv, bq, bk, bv, Wt3, bias_t);
    proj_kernel<<<512, 384, 0, stream>>>(x, Wt3, bias_t, qsb, ksb, vtb);
    attn_kernel<<<256, 768, 0, stream>>>(qsb, ksb, vtb, out);
}

// Round 18
// 49.160 us; speedup vs baseline: 1.4026x; 1.0204x over previous
//
#include <hip/hip_runtime.h>
#include <hip/hip_bf16.h>

// AttentionHead: B=4, T=4096, D=1024, DA=64, scale = 1/96 folded into q.
// R18 = R17 + ONE change: proj counted-vmcnt DMA pipeline (T4). 3 LDS
// buffers, DMA issued 2 stages ahead, B prefetched 1 stage ahead into
// registers; raw s_barrier with s_waitcnt vmcnt(N) lgkmcnt(0), N = in-
// flight FUTURE loads (never 0 in-loop) -> the barrier proves DMA(kt+1)
// landed without draining DMA(kt+2)/B(kt+1). attn/prep = R17 verbatim.

#define T_SEQ 4096
#define NW 12   // attention waves per block (3/SIMD; unified-reg cap 170)

using bf16x8 = __bf16 __attribute__((ext_vector_type(8)));
using f32x16 = float __attribute__((ext_vector_type(16)));
using uint4v = unsigned int __attribute__((ext_vector_type(4)));

static constexpr float QSCALE = 1.4426950408889634f / 96.0f;

__device__ __forceinline__ unsigned short bf1(float v) {
    unsigned u = __builtin_bit_cast(unsigned, v);
    u += 0x7FFFu + ((u >> 16) & 1u);
    return (unsigned short)(u >> 16);
}
__device__ __forceinline__ unsigned cvt2(float lo, float hi) {
    unsigned r;
    asm("v_cvt_pk_bf16_f32 %0, %1, %2" : "=v"(r) : "v"(lo), "v"(hi));
    return r;
}
// v_permlane32_swap: ONLY safe when a,b hold DISTINCT values (see R8 note).
__device__ __forceinline__ void pswap(unsigned& a, unsigned& b) {
    asm volatile("v_permlane32_swap_b32 %0, %1" : "+v"(a), "+v"(b));
}
__device__ __forceinline__ float bflo(unsigned u) {
    return __builtin_bit_cast(float, u << 16);
}
__device__ __forceinline__ float bfhi(unsigned u) {
    return __builtin_bit_cast(float, u & 0xFFFF0000u);
}
__device__ __forceinline__ f32x16 zero16() {
    f32x16 z;
#pragma unroll
    for (int i = 0; i < 16; ++i) z[i] = 0.0f;
    return z;
}
#define MFMA32(a, b, c) __builtin_amdgcn_mfma_f32_32x32x16_bf16(a, b, c, 0, 0, 0)

// async global -> LDS, 16B per lane (dest = wave-uniform base + lane*16)
__device__ __forceinline__ void gload_lds16(const float* g, float* l) {
    __builtin_amdgcn_global_load_lds(
        (const __attribute__((address_space(1))) float*)g,
        (__attribute__((address_space(3))) float*)l, 16, 0, 0);
}

// ---------------- kernel 1: W -> Wt3 frag-linear bf16 ----------------
// Wt3 flat: ((kt*6 + ct)*4 + kk)*512 + lane*8 + e
//   where col cg = ct*32 + (lane&31), k = kt*64 + kk*16 + (lane>>5)*8 + e.
__global__ __launch_bounds__(256) void prep_w(
        const float* __restrict__ Wq, const float* __restrict__ Wk,
        const float* __restrict__ Wv, const float* __restrict__ bq,
        const float* __restrict__ bk, const float* __restrict__ bv,
        unsigned short* __restrict__ Wt3, float* __restrict__ bias_t) {
    __shared__ float tile[64][65];
    const int tid = threadIdx.x;
    const int m = blockIdx.x >> 4, kt = blockIdx.x & 15, d0 = kt * 64;
    const float* W = (m == 0) ? Wq : (m == 1) ? Wk : Wv;
    const int a = tid & 63, r4 = tid >> 6;
#pragma unroll
    for (int j = 0; j < 16; ++j) {
        const int rr = r4 + 4 * j;
        tile[rr][a] = W[(size_t)(d0 + rr) * 64 + a];
    }
    __syncthreads();
    const float scl = (m == 0) ? QSCALE : 1.0f;
    const int dc = tid & 63, ar = tid >> 6;
#pragma unroll
    for (int j = 0; j < 16; ++j) {
        const int aa = ar + 4 * j;
        const int cg = m * 64 + aa;
        const size_t addr =
            ((size_t)(kt * 6 + (cg >> 5)) * 4 + (dc >> 4)) * 512 +
            ((cg & 31) + 32 * ((dc >> 3) & 1)) * 8 + (dc & 7);
        Wt3[addr] = bf1(tile[dc][aa] * scl);
    }
    if (kt == 0 && tid < 64) {
        const float* bb = (m == 0) ? bq : (m == 1) ? bk : bv;
        bias_t[m * 64 + tid] = bb[tid] * scl;
    }
}

// ---------------- kernel 2: QKV projection (v8: counted-vmcnt DMA) --------
// 512 blocks x 384 thr = 6 waves (ct 0..5). 32 rows/block, full K=1024,
// 16 stages. 3-buffer DMA (2 ahead), B regs (1 ahead). Per-stage vmem
// order: [B(kt+1) x4, DMA(kt+2) x1-2]; barrier waits vmcnt(5/6) so only
// DMA(kt+1) is proven landed. Source-swizzled 16B blocks as in R17.
__global__ __launch_bounds__(384, 3) void proj_kernel(
        const float* __restrict__ x, const unsigned short* __restrict__ Wt3,
        const float* __restrict__ bias_t, unsigned short* __restrict__ qs,
        unsigned short* __restrict__ ksf, unsigned short* __restrict__ vtf) {
    __shared__ float Ald[3][2048];   // [buf][32 rows x 64 f32] = 3 x 8 KB

    const int tid = threadIdx.x;
    const int w = tid >> 6, l = tid & 63, g = l >> 5, c32 = l & 31;
    const int ct = w;                     // 6 waves = 6 col-tiles
    const int rowbase = blockIdx.x * 32;

    // DMA call j covers rows 4j..4j+3 (1 KB). wave w: call w; waves 0,1
    // also take calls 6,7. lane l: row = 4j+(l>>4), dest blk = l&15,
    // SOURCE blk = (l&15) ^ (row&7)  [involution; read applies same XOR].
    const int j1 = w;
    const int row1 = 4 * j1 + (l >> 4);
    const float* gp1 = x + (size_t)(rowbase + row1) * 1024 +
                       (((l & 15) ^ (row1 & 7)) << 2);
    const bool has2 = (w < 2);
    const int j2 = 6 + w;
    const int row2 = 4 * j2 + (l >> 4);
    const float* gp2 = x + (size_t)(rowbase + row2) * 1024 +
                       (((l & 15) ^ (row2 & 7)) << 2);

    const unsigned short* Wb = Wt3 + (size_t)(ct * 4) * 512 + l * 8;

    f32x16 acc = zero16();
    bf16x8 bA[4], bB[4];   // B register double-buffer (1 stage ahead)

    // prologue: DMA stages 0,1 -> buf 0,1; B(0) -> bA.
    gload_lds16(gp1, &Ald[0][j1 * 256]);
    if (has2) gload_lds16(gp2, &Ald[0][j2 * 256]);
    gload_lds16(gp1 + 64, &Ald[1][j1 * 256]);
    if (has2) gload_lds16(gp2 + 64, &Ald[1][j2 * 256]);
#pragma unroll
    for (int f = 0; f < 4; ++f) bA[f] = *(const bf16x8*)(Wb + f * 512);
    // need D0 retired; allow D1 + B(0) (+D1b) to stay in flight
    if (has2) asm volatile("s_waitcnt vmcnt(6)" ::: "memory");
    else      asm volatile("s_waitcnt vmcnt(5)" ::: "memory");
    __builtin_amdgcn_s_barrier();
    __builtin_amdgcn_sched_barrier(0);

    auto STAGE = [&](bf16x8(&bc)[4], bf16x8(&bn)[4], int kt) {
        // (1) B loads for stage kt+1 (consumed next stage, no wait then)
        if (kt < 15) {
            const unsigned short* Wn = Wb + (size_t)(kt + 1) * 12288;
#pragma unroll
            for (int f = 0; f < 4; ++f) bn[f] = *(const bf16x8*)(Wn + f * 512);
        }
        // (2) DMA stage kt+2 into buf (kt+2)%3 == (kt-1)%3 (readers done
        //     under the PREVIOUS barrier's lgkmcnt(0))
        if (kt < 14) {
            gload_lds16(gp1 + (kt + 2) * 64, &Ald[(kt + 2) % 3][j1 * 256]);
            if (has2)
                gload_lds16(gp2 + (kt + 2) * 64, &Ald[(kt + 2) % 3][j2 * 256]);
        }
        // (3) ds_read fp32 frags (swizzled) + convert + MFMA (bc preloaded)
        const float* A = Ald[kt % 3];
#pragma unroll
        for (int kk = 0; kk < 4; ++kk) {
            const int blk = kk * 4 + g * 2;
            float4 f0 = *(const float4*)(A + c32 * 64 + ((blk ^ (c32 & 7)) << 2));
            float4 f1 = *(const float4*)(A + c32 * 64 + (((blk + 1) ^ (c32 & 7)) << 2));
            uint4v ua;
            ua[0] = cvt2(f0.x, f0.y); ua[1] = cvt2(f0.z, f0.w);
            ua[2] = cvt2(f1.x, f1.y); ua[3] = cvt2(f1.z, f1.w);
            bf16x8 af = __builtin_bit_cast(bf16x8, ua);
            acc = MFMA32(af, bc[kk], acc);
        }
        // (4) counted wait + raw barrier: prove DMA(kt+1) landed, keep
        //     B(kt+1) + DMA(kt+2) in flight. NEVER vmcnt(0) mid-loop.
        if (kt < 14) {
            if (has2) asm volatile("s_waitcnt vmcnt(6) lgkmcnt(0)" ::: "memory");
            else      asm volatile("s_waitcnt vmcnt(5) lgkmcnt(0)" ::: "memory");
            __builtin_amdgcn_s_barrier();
            __builtin_amdgcn_sched_barrier(0);
        } else if (kt == 14) {
            asm volatile("s_waitcnt vmcnt(4) lgkmcnt(0)" ::: "memory");
            __builtin_amdgcn_s_barrier();
            __builtin_amdgcn_sched_barrier(0);
        }
        // kt == 15: no barrier needed (only acc consumed after)
    };

#pragma unroll
    for (int kt = 0; kt < 16; kt += 2) {
        STAGE(bA, bB, kt);
        STAGE(bB, bA, kt + 1);
    }

    // epilogue (unchanged)
    const int cg = ct * 32 + c32;
    const float bias = bias_t[cg];
    const int mat = cg >> 6, cm = cg & 63;
    if (mat == 2) {
#pragma unroll
        for (int q4 = 0; q4 < 4; ++q4) {
            const int rowg = rowbase + 8 * q4 + 4 * g;
            const int b = rowg >> 12, tl = rowg & (T_SEQ - 1);
            const int ch = tl >> 5;
            const int f = (cm >> 5) * 2 + (q4 >> 1);
            const int lane = (cm & 31) + 32 * (q4 & 1);
            unsigned lo = cvt2(acc[4 * q4 + 0] + bias, acc[4 * q4 + 1] + bias);
            unsigned hi = cvt2(acc[4 * q4 + 2] + bias, acc[4 * q4 + 3] + bias);
            *(uint2*)(vtf + ((size_t)b * 128 + ch) * 2048 + f * 512 +
                      lane * 8 + 4 * g) = make_uint2(lo, hi);
        }
    } else if (mat == 1) {
#pragma unroll
        for (int r = 0; r < 16; ++r) {
            const int rowg = rowbase + (r & 3) + 8 * (r >> 2) + 4 * g;
            const int b = rowg >> 12, tl = rowg & (T_SEQ - 1);
            ksf[((size_t)b * 128 + (tl >> 5)) * 2048 + (cm >> 4) * 512 +
                ((tl & 31) + 32 * ((cm >> 3) & 1)) * 8 + (cm & 7)] =
                bf1(acc[r] + bias);
        }
    } else {
#pragma unroll
        for (int r = 0; r < 16; ++r) {
            const int rowg = rowbase + (r & 3) + 8 * (r >> 2) + 4 * g;
            qs[(size_t)rowg * 64 + cm] = bf1(acc[r] + bias);
        }
    }
}

// ---------------- kernel 3: causal flash attention (R13 verbatim) --------
__global__ __launch_bounds__(768, 3) void attn_kernel(
        const unsigned short* __restrict__ qs, const unsigned short* __restrict__ ksf,
        const unsigned short* __restrict__ vtf, float* __restrict__ out) {
    __shared__ unsigned short Osh[NW][32][66];
    __shared__ float msh[NW][32];
    __shared__ float ssh[NW][32];

    const int tid = threadIdx.x;
    const int w = tid >> 6, l = tid & 63, g = l >> 5, c32 = l & 31;
    const int b = blockIdx.x & 3;
    const int pid = blockIdx.x >> 2;

    for (int tt = 0; tt < 2; ++tt) {
        const int jt = tt ? pid : 127 - pid;
        const int qbase = jt * 32;

        const unsigned short* qp =
            qs + ((size_t)b * T_SEQ + qbase + c32) * 64 + g * 8;
        bf16x8 qf[4];
#pragma unroll
        for (int t = 0; t < 4; ++t) qf[t] = *(const bf16x8*)(qp + 16 * t);

        const unsigned short* pKc = ksf + ((size_t)b * 128 + w) * 2048 + l * 8;
        const unsigned short* pVc = vtf + ((size_t)b * 128 + w) * 2048 + l * 8;

        auto loadK = [&](bf16x8(&kf)[4]) {
#pragma unroll
            for (int t = 0; t < 4; ++t)
                kf[t] = *(const bf16x8*)(pKc + t * 512);
            pKc += NW * 2048;
        };
        auto loadV = [&](bf16x8(&vf)[4]) {
#pragma unroll
            for (int f = 0; f < 4; ++f)
                vf[f] = *(const bf16x8*)(pVc + f * 512);
            pVc += NW * 2048;
        };

        const int nch = (jt >= w) ? (jt - w) / NW + 1 : 0;
        const bool hasDiag = (jt >= w) && ((jt - w) % NW == 0);
        float m = -INFINITY, ssum = 0.0f;
        f32x16 o0 = zero16(), o1 = zero16();
        f32x16 s_cur;
        bf16x8 k0[4], k1[4], vR[4];

        if (nch > 0) {
            loadK(k0);
            f32x16 t = zero16();
#pragma unroll
            for (int t4 = 0; t4 < 4; ++t4) t = MFMA32(k0[t4], qf[t4], t);
            s_cur = t;
        }

        auto STEP = [&](bf16x8(&kn)[4], int i) {
            loadV(vR);
            if (i + 1 < nch) loadK(kn);
            if (hasDiag && i == nch - 1) {
#pragma unroll
                for (int r = 0; r < 16; ++r) {
                    const int kl = (r & 3) + 8 * (r >> 2) + 4 * g;
                    if (kl > c32) s_cur[r] = -1e30f;
                }
            }
            float a0 = fmaxf(fmaxf(s_cur[0], s_cur[1]), fmaxf(s_cur[2], s_cur[3]));
            float a1 = fmaxf(fmaxf(s_cur[4], s_cur[5]), fmaxf(s_cur[6], s_cur[7]));
            float a2 = fmaxf(fmaxf(s_cur[8], s_cur[9]), fmaxf(s_cur[10], s_cur[11]));
            float a3 = fmaxf(fmaxf(s_cur[12], s_cur[13]), fmaxf(s_cur[14], s_cur[15]));
            float pm = fmaxf(fmaxf(a0, a1), fmaxf(a2, a3));
            if (!__all(pm <= m + 8.0f)) {
                float rmax = fmaxf(pm, __shfl_xor(pm, 32, 64));
                const float mn = fmaxf(m, rmax);
                const float alpha = exp2f(m - mn);
#pragma unroll
                for (int r = 0; r < 16; ++r) { o0[r] *= alpha; o1[r] *= alpha; }
                ssum *= alpha;
                m = mn;
            }
            float p[16];
#pragma unroll
            for (int r = 0; r < 16; ++r) p[r] = exp2f(s_cur[r] - m);
            float s0 = (p[0] + p[1]) + (p[2] + p[3]);
            float s1 = (p[4] + p[5]) + (p[6] + p[7]);
            float s2 = (p[8] + p[9]) + (p[10] + p[11]);
            float s3 = (p[12] + p[13]) + (p[14] + p[15]);
            ssum += (s0 + s1) + (s2 + s3);
            unsigned c01 = cvt2(p[0], p[1]), c23 = cvt2(p[2], p[3]);
            unsigned c45 = cvt2(p[4], p[5]), c67 = cvt2(p[6], p[7]);
            pswap(c01, c45); pswap(c23, c67);
            unsigned c89 = cvt2(p[8], p[9]), cab = cvt2(p[10], p[11]);
            unsigned ccd = cvt2(p[12], p[13]), cef = cvt2(p[14], p[15]);
            pswap(c89, ccd); pswap(cab, cef);
            uint4v u0; u0[0] = c01; u0[1] = c23; u0[2] = c45; u0[3] = c67;
            uint4v u1; u1[0] = c89; u1[1] = cab; u1[2] = ccd; u1[3] = cef;
            bf16x8 pb0 = __builtin_bit_cast(bf16x8, u0);
            bf16x8 pb1 = __builtin_bit_cast(bf16x8, u1);
            __builtin_amdgcn_s_setprio(1);
            o0 = MFMA32(vR[0], pb0, o0);
            o0 = MFMA32(vR[1], pb1, o0);
            o1 = MFMA32(vR[2], pb0, o1);
            o1 = MFMA32(vR[3], pb1, o1);
            if (i + 1 < nch) {
                f32x16 t = zero16();
#pragma unroll
                for (int t4 = 0; t4 < 4; ++t4) t = MFMA32(kn[t4], qf[t4], t);
                s_cur = t;
            }
            __builtin_amdgcn_s_setprio(0);
        };

        int i = 0;
        while (i < nch) {
            STEP(k1, i); ++i;
            if (i < nch) { STEP(k0, i); ++i; }
        }
        ssum += __shfl_xor(ssum, 32, 64);

        if (l < 32) { msh[w][l] = m; ssh[w][l] = ssum; }
#pragma unroll
        for (int q4 = 0; q4 < 4; ++q4) {
            const int base = 8 * q4 + 4 * g;
            *(unsigned*)&Osh[w][c32][base]      = cvt2(o0[4 * q4], o0[4 * q4 + 1]);
            *(unsigned*)&Osh[w][c32][base + 2]  = cvt2(o0[4 * q4 + 2], o0[4 * q4 + 3]);
            *(unsigned*)&Osh[w][c32][base + 32] = cvt2(o1[4 * q4], o1[4 * q4 + 1]);
            *(unsigned*)&Osh[w][c32][base + 34] = cvt2(o1[4 * q4 + 2], o1[4 * q4 + 3]);
        }
        __syncthreads();

        if (tid < 512) {
            const int qrow = tid >> 4, e4 = tid & 15;
            float M = -INFINITY;
            float mw[NW];
#pragma unroll
            for (int u = 0; u < NW; ++u) { mw[u] = msh[u][qrow]; M = fmaxf(M, mw[u]); }
            float den = 0.0f;
            float r0 = 0.f, r1 = 0.f, r2 = 0.f, r3 = 0.f;
#pragma unroll
            for (int u = 0; u < NW; ++u) {
                const float scu = exp2f(mw[u] - M);
                den += ssh[u][qrow] * scu;
                const unsigned ua = *(const unsigned*)&Osh[u][qrow][4 * e4];
                const unsigned ub = *(const unsigned*)&Osh[u][qrow][4 * e4 + 2];
                r0 += bflo(ua) * scu;
                r1 += bfhi(ua) * scu;
                r2 += bflo(ub) * scu;
                r3 += bfhi(ub) * scu;
            }
            const float inv = 1.0f / den;
            float4 st;
            st.x = r0 * inv; st.y = r1 * inv; st.z = r2 * inv; st.w = r3 * inv;
            *(float4*)(out + ((size_t)b * T_SEQ + qbase + qrow) * 64 + 4 * e4) = st;
        }
        __syncthreads();
    }
}

// ---------------- launch ----------------
extern "C" void kernel_launch(void* const* d_in, const int* in_sizes, int n_in,
                              void* d_out, int out_size, void* d_ws, size_t ws_size,
                              hipStream_t stream) {
    const float* x  = (const float*)d_in[0];
    const float* Wq = (const float*)d_in[1];
    const float* bq = (const float*)d_in[2];
    const float* Wk = (const float*)d_in[3];
    const float* bk = (const float*)d_in[4];
    const float* Wv = (const float*)d_in[5];
    const float* bv = (const float*)d_in[6];
    float* out = (float*)d_out;

    char* ws = (char*)d_ws;
    unsigned short* Wt3    = (unsigned short*)(ws);                 // 384 KB
    float*          bias_t = (float*)(ws + 393216);                 // 768 B
    unsigned short* qsb    = (unsigned short*)(ws + (1u << 20));    // 2 MB
    unsigned short* ksb    = (unsigned short*)(ws + (3u << 20));    // 2 MB
    unsigned short* vtb    = (unsigned short*)(ws + (5u << 20));    // 2 MB

    prep_w<<<48, 256, 0, stream>>>(Wq, Wk, Wv, bq, bk, bv, Wt3, bias_t);
    proj_kernel<<<512, 384, 0, stream>>>(x, Wt3, bias_t, qsb, ksb, vtb);
    attn_kernel<<<256, 768, 0, stream>>>(qsb, ksb, vtb, out);
}